// Round 2
// baseline (1168.150 us; speedup 1.0000x reference)
//
#include <hip/hip_runtime.h>

#define N_NODES 20000
#define N_EDGES 100000
#define DIM 32
#define R2 100
#define NLAYERS 4
#define BATCH 4
#define NEG 32
#define NREP 3
#define BS (NREP * BATCH)          // 12
#define RELDIM (R2 * DIM)          // 3200

// ---------------- workspace layout (floats then ints) ----------------
#define XO_A 0
#define XO_B (XO_A + (size_t)BS * N_NODES * DIM)
#define PBO_A (XO_B + (size_t)BS * N_NODES * DIM)
#define PBO_B (PBO_A + (size_t)BS * N_NODES)
#define RELO (PBO_B + (size_t)BS * N_NODES)
#define QO (RELO + (size_t)BS * RELDIM)
#define FLOAT_TOTAL (QO + (size_t)BS * DIM)

#define IO_H0 0
#define IO_TIDX (IO_H0 + BS)
#define IO_COUNTS (IO_TIDX + BS * NEG)
#define IO_OFF (IO_COUNTS + N_NODES)
#define IO_CURSOR (IO_OFF + N_NODES + 1)
#define IO_PERM (IO_CURSOR + N_NODES)
#define INT_TOTAL (IO_PERM + N_EDGES)

// ---------------------------------------------------------------------
__global__ void k_init(const int* __restrict__ batch,
                       const float* __restrict__ start_query,
                       float* __restrict__ x, float* __restrict__ pb,
                       float* __restrict__ q, int* __restrict__ h0,
                       int* __restrict__ t_idx) {
    int r = threadIdx.x;
    if (r >= BS) return;
    int b = r % BATCH, rep = r / BATCH;
    int h00 = batch[(b * NEG + 0) * 2 + 0];
    bool is_t_neg = true;
    for (int j = 0; j < NEG; j++)
        if (batch[(b * NEG + j) * 2 + 0] != h00) { is_t_neg = false; break; }
    int hsel = is_t_neg ? 0 : 1;
    int h0v = batch[(b * NEG + 0) * 2 + hsel];
    h0[r] = h0v;
    for (int j = 0; j < NEG; j++)
        t_idx[r * NEG + j] = batch[(b * NEG + j) * 2 + (1 - hsel)];
    for (int d = 0; d < DIM; d++) {
        float qv = start_query[rep * DIM + d];
        q[r * DIM + d] = qv;
        x[((size_t)r * N_NODES + h0v) * DIM + d] = qv;
    }
    pb[(size_t)r * N_NODES + h0v] = 1.0f;
}

__global__ void k_count(const int* __restrict__ dst, int* __restrict__ counts) {
    int e = blockIdx.x * blockDim.x + threadIdx.x;
    if (e < N_EDGES) atomicAdd(&counts[dst[e]], 1);
}

__global__ void k_scan(const int* __restrict__ counts, int* __restrict__ off,
                       int* __restrict__ cursor) {
    __shared__ int sd[1024];
    int t = threadIdx.x;
    const int CH = (N_NODES + 1023) / 1024;  // 20
    int base = t * CH;
    int sum = 0;
    for (int i = 0; i < CH; i++) {
        int idx = base + i;
        if (idx < N_NODES) sum += counts[idx];
    }
    sd[t] = sum;
    __syncthreads();
    for (int o = 1; o < 1024; o <<= 1) {
        int v = (t >= o) ? sd[t - o] : 0;
        __syncthreads();
        sd[t] += v;
        __syncthreads();
    }
    int excl = sd[t] - sum;
    int run = excl;
    for (int i = 0; i < CH; i++) {
        int idx = base + i;
        if (idx < N_NODES) {
            off[idx] = run;
            cursor[idx] = run;
            run += counts[idx];
        }
    }
    if (t == 1023) off[N_NODES] = sd[1023];
}

__global__ void k_place(const int* __restrict__ dst, int* __restrict__ cursor,
                        int* __restrict__ perm) {
    int e = blockIdx.x * blockDim.x + threadIdx.x;
    if (e < N_EDGES) {
        int p = atomicAdd(&cursor[dst[e]], 1);
        perm[p] = e;
    }
}

// rel[r, c] = b_rel_l[c] + sum_k q[r,k] * W_rel_l[k, c]   (c = rt*DIM + d)
__global__ void k_rel(const float* __restrict__ q, const float* __restrict__ W_rel_l,
                      const float* __restrict__ b_rel_l, float* __restrict__ rel) {
    int idx = blockIdx.x * blockDim.x + threadIdx.x;
    if (idx >= BS * RELDIM) return;
    int r = idx / RELDIM;
    int c = idx % RELDIM;
    float acc = b_rel_l[c];
    #pragma unroll
    for (int k = 0; k < DIM; k++) acc += q[r * DIM + k] * W_rel_l[k * RELDIM + c];
    rel[idx] = acc;
}

// Fused: message gather (CSR) + boundary add + concat-linear-ReLU + pb scatter-max
__launch_bounds__(256)
__global__ void k_layer(const float* __restrict__ x_old, const float* __restrict__ pb_old,
                        const float* __restrict__ rel, const float* __restrict__ edge_attr,
                        const int* __restrict__ src, const int* __restrict__ etype,
                        const int* __restrict__ off, const int* __restrict__ perm,
                        const int* __restrict__ h0, const float* __restrict__ q,
                        const float* __restrict__ W_lin_l, const float* __restrict__ b_lin_l,
                        float* __restrict__ x_new, float* __restrict__ pb_new) {
    __shared__ float Wl[64 * DIM];
    __shared__ float bl[DIM];
    for (int i = threadIdx.x; i < 64 * DIM; i += blockDim.x) Wl[i] = W_lin_l[i];
    if (threadIdx.x < DIM) bl[threadIdx.x] = b_lin_l[threadIdx.x];
    __syncthreads();

    int idx = blockIdx.x * blockDim.x + threadIdx.x;
    if (idx >= BS * N_NODES) return;
    int r = idx / N_NODES;
    int n = idx % N_NODES;

    const float4* xrow4 = (const float4*)(x_old + (size_t)idx * DIM);
    float4 xr[8], ag[8];
    #pragma unroll
    for (int c = 0; c < 8; c++) {
        xr[c] = xrow4[c];
        ag[c] = make_float4(0.f, 0.f, 0.f, 0.f);
    }
    float pbm = pb_old[idx];

    int s0 = off[n], s1 = off[n + 1];
    const float* xbase = x_old + (size_t)r * N_NODES * DIM;
    const float* pbbase = pb_old + (size_t)r * N_NODES;
    const float* relr = rel + (size_t)r * RELDIM;
    for (int k = s0; k < s1; k++) {
        int e = perm[k];
        int s = src[e];
        int et = etype[e];
        const float4* xs = (const float4*)(xbase + (size_t)s * DIM);
        const float4* rl = (const float4*)(relr + (size_t)et * DIM);
        const float4* ea = (const float4*)(edge_attr + (size_t)e * DIM);
        #pragma unroll
        for (int c = 0; c < 8; c++) {
            float4 a = xs[c], bb = rl[c], t = ea[c];
            ag[c].x += a.x * (bb.x + t.x);
            ag[c].y += a.y * (bb.y + t.y);
            ag[c].z += a.z * (bb.z + t.z);
            ag[c].w += a.w * (bb.w + t.w);
        }
        pbm = fmaxf(pbm, pbbase[s]);
    }
    if (n == h0[r]) {
        const float4* qq = (const float4*)(q + r * DIM);
        #pragma unroll
        for (int c = 0; c < 8; c++) {
            float4 v = qq[c];
            ag[c].x += v.x; ag[c].y += v.y; ag[c].z += v.z; ag[c].w += v.w;
        }
    }

    const float* xrf = (const float*)xr;
    const float* agf = (const float*)ag;
    float* xo = x_new + (size_t)idx * DIM;
    #pragma unroll
    for (int j0 = 0; j0 < DIM; j0 += 4) {
        float acc[4];
        #pragma unroll
        for (int jj = 0; jj < 4; jj++) {
            float a = bl[j0 + jj];
            #pragma unroll
            for (int k = 0; k < DIM; k++) a += xrf[k] * Wl[k * DIM + j0 + jj];
            #pragma unroll
            for (int k = 0; k < DIM; k++) a += agf[k] * Wl[(DIM + k) * DIM + j0 + jj];
            acc[jj] = fmaxf(a, 0.f);
        }
        float4 o = make_float4(acc[0], acc[1], acc[2], acc[3]);
        *(float4*)(xo + j0) = o;
    }
    pb_new[idx] = pbm;
}

__global__ void k_final(const float* __restrict__ x, const float* __restrict__ pb,
                        const int* __restrict__ t_idx,
                        const float* __restrict__ W1, const float* __restrict__ b1,
                        const float* __restrict__ W2, const float* __restrict__ b2,
                        float* __restrict__ out) {
    int i = threadIdx.x;  // 0..127 = b*NEG + neg
    if (i >= BATCH * NEG) return;
    int b = i / NEG, j = i % NEG;
    int t = t_idx[b * NEG + j];  // same across reps
    float feat[DIM];
    #pragma unroll
    for (int d = 0; d < DIM; d++) feat[d] = 0.f;
    for (int rep = 0; rep < NREP; rep++) {
        const float* xr = x + ((size_t)(rep * BATCH + b) * N_NODES + t) * DIM;
        #pragma unroll
        for (int d = 0; d < DIM; d++) feat[d] += xr[d];
    }
    #pragma unroll
    for (int d = 0; d < DIM; d++) feat[d] *= (1.f / 3.f);
    float hid[DIM];
    #pragma unroll
    for (int jj = 0; jj < DIM; jj++) {
        float a = b1[jj];
        #pragma unroll
        for (int k = 0; k < DIM; k++) a += feat[k] * W1[k * DIM + jj];
        hid[jj] = fmaxf(a, 0.f);
    }
    #pragma unroll
    for (int jj = 0; jj < DIM; jj++) {
        float a = b2[jj];
        #pragma unroll
        for (int k = 0; k < DIM; k++) a += hid[k] * W2[k * DIM + jj];
        out[(size_t)i * DIM + jj] = a;
    }
    float pm = 0.f;
    for (int rep = 0; rep < NREP; rep++)
        pm = fmaxf(pm, pb[(size_t)(rep * BATCH + b) * N_NODES + t]);
    out[(size_t)BATCH * NEG * DIM + i] = pm;
}

// ---------------------------------------------------------------------
extern "C" void kernel_launch(void* const* d_in, const int* in_sizes, int n_in,
                              void* d_out, int out_size, void* d_ws, size_t ws_size,
                              hipStream_t stream) {
    const int* batch = (const int*)d_in[0];
    const int* edge_index = (const int*)d_in[1];
    const int* edge_type = (const int*)d_in[2];
    const float* edge_attr = (const float*)d_in[3];
    // d_in[4] = num_nodes (hard-coded N_NODES, fixed by setup)
    const float* start_query = (const float*)d_in[5];
    const float* W_rel = (const float*)d_in[6];
    const float* b_rel = (const float*)d_in[7];
    const float* W_lin = (const float*)d_in[8];
    const float* b_lin = (const float*)d_in[9];
    const float* W_mlp1 = (const float*)d_in[10];
    const float* b_mlp1 = (const float*)d_in[11];
    const float* W_mlp2 = (const float*)d_in[12];
    const float* b_mlp2 = (const float*)d_in[13];

    float* wf = (float*)d_ws;
    int* wi = (int*)(wf + FLOAT_TOTAL);
    size_t need = FLOAT_TOTAL * sizeof(float) + INT_TOTAL * sizeof(int);
    if (ws_size < need) return;  // fail loudly via correctness check

    float* x_a = wf + XO_A;
    float* x_b = wf + XO_B;
    float* pb_a = wf + PBO_A;
    float* pb_b = wf + PBO_B;
    float* rel = wf + RELO;
    float* q = wf + QO;
    int* h0 = wi + IO_H0;
    int* t_idx = wi + IO_TIDX;
    int* counts = wi + IO_COUNTS;
    int* off = wi + IO_OFF;
    int* cursor = wi + IO_CURSOR;
    int* perm = wi + IO_PERM;

    const int* src = edge_index;
    const int* dst = edge_index + N_EDGES;

    // zero what must be zero (ws is poisoned before every call)
    hipMemsetAsync(x_a, 0, (size_t)BS * N_NODES * DIM * sizeof(float), stream);
    hipMemsetAsync(pb_a, 0, (size_t)BS * N_NODES * sizeof(float), stream);
    hipMemsetAsync(counts, 0, (size_t)N_NODES * sizeof(int), stream);

    k_init<<<1, 64, 0, stream>>>(batch, start_query, x_a, pb_a, q, h0, t_idx);

    // CSR by dst
    int eb = (N_EDGES + 255) / 256;
    k_count<<<eb, 256, 0, stream>>>(dst, counts);
    k_scan<<<1, 1024, 0, stream>>>(counts, off, cursor);
    k_place<<<eb, 256, 0, stream>>>(dst, cursor, perm);

    float* x_cur = x_a;
    float* x_nxt = x_b;
    float* pb_cur = pb_a;
    float* pb_nxt = pb_b;
    int relb = (BS * RELDIM + 255) / 256;
    int nb = (BS * N_NODES + 255) / 256;
    for (int l = 0; l < NLAYERS; l++) {
        k_rel<<<relb, 256, 0, stream>>>(q, W_rel + (size_t)l * DIM * RELDIM,
                                        b_rel + (size_t)l * RELDIM, rel);
        k_layer<<<nb, 256, 0, stream>>>(x_cur, pb_cur, rel, edge_attr, src, edge_type,
                                        off, perm, h0, q,
                                        W_lin + (size_t)l * 64 * DIM,
                                        b_lin + (size_t)l * DIM,
                                        x_nxt, pb_nxt);
        float* tx = x_cur; x_cur = x_nxt; x_nxt = tx;
        float* tp = pb_cur; pb_cur = pb_nxt; pb_nxt = tp;
    }

    k_final<<<1, 128, 0, stream>>>(x_cur, pb_cur, t_idx, W_mlp1, b_mlp1, W_mlp2, b_mlp2,
                                   (float*)d_out);
}

// Round 3
// 622.756 us; speedup vs baseline: 1.8758x; 1.8758x over previous
//
#include <hip/hip_runtime.h>

#define N_NODES 20000
#define N_EDGES 100000
#define DIM 32
#define R2 100
#define NLAYERS 4
#define BATCH 4
#define NEG 32
#define NREP 3
#define BS (NREP * BATCH)          // 12
#define RELDIM (R2 * DIM)          // 3200

// ---------------- workspace layout (floats then ints) ----------------
#define XO_A 0
#define XO_B (XO_A + (size_t)BS * N_NODES * DIM)
#define PBO_A (XO_B + (size_t)BS * N_NODES * DIM)
#define PBO_B (PBO_A + (size_t)BS * N_NODES)
#define RELO (PBO_B + (size_t)BS * N_NODES)
#define QO (RELO + (size_t)BS * RELDIM)
#define FLOAT_TOTAL (QO + (size_t)BS * DIM)

#define IO_H0 0
#define IO_TIDX (IO_H0 + BS)
#define IO_COUNTS (IO_TIDX + BS * NEG)
#define IO_OFF (IO_COUNTS + N_NODES)
#define IO_CURSOR (IO_OFF + N_NODES + 1)
#define IO_PERM (IO_CURSOR + N_NODES)
#define INT_TOTAL (IO_PERM + N_EDGES)

// ---------------------------------------------------------------------
__global__ void k_init(const int* __restrict__ batch,
                       const float* __restrict__ start_query,
                       float* __restrict__ x, float* __restrict__ pb,
                       float* __restrict__ q, int* __restrict__ h0,
                       int* __restrict__ t_idx) {
    int r = threadIdx.x;
    if (r >= BS) return;
    int b = r % BATCH, rep = r / BATCH;
    int h00 = batch[(b * NEG + 0) * 2 + 0];
    bool is_t_neg = true;
    for (int j = 0; j < NEG; j++)
        if (batch[(b * NEG + j) * 2 + 0] != h00) { is_t_neg = false; break; }
    int hsel = is_t_neg ? 0 : 1;
    int h0v = batch[(b * NEG + 0) * 2 + hsel];
    h0[r] = h0v;
    for (int j = 0; j < NEG; j++)
        t_idx[r * NEG + j] = batch[(b * NEG + j) * 2 + (1 - hsel)];
    for (int d = 0; d < DIM; d++) {
        float qv = start_query[rep * DIM + d];
        q[r * DIM + d] = qv;
        x[((size_t)r * N_NODES + h0v) * DIM + d] = qv;
    }
    pb[(size_t)r * N_NODES + h0v] = 1.0f;
}

__global__ void k_count(const int* __restrict__ dst, int* __restrict__ counts) {
    int e = blockIdx.x * blockDim.x + threadIdx.x;
    if (e < N_EDGES) atomicAdd(&counts[dst[e]], 1);
}

__global__ void k_scan(const int* __restrict__ counts, int* __restrict__ off,
                       int* __restrict__ cursor) {
    __shared__ int sd[1024];
    int t = threadIdx.x;
    const int CH = (N_NODES + 1023) / 1024;  // 20
    int base = t * CH;
    int sum = 0;
    for (int i = 0; i < CH; i++) {
        int idx = base + i;
        if (idx < N_NODES) sum += counts[idx];
    }
    sd[t] = sum;
    __syncthreads();
    for (int o = 1; o < 1024; o <<= 1) {
        int v = (t >= o) ? sd[t - o] : 0;
        __syncthreads();
        sd[t] += v;
        __syncthreads();
    }
    int excl = sd[t] - sum;
    int run = excl;
    for (int i = 0; i < CH; i++) {
        int idx = base + i;
        if (idx < N_NODES) {
            off[idx] = run;
            cursor[idx] = run;
            run += counts[idx];
        }
    }
    if (t == 1023) off[N_NODES] = sd[1023];
}

__global__ void k_place(const int* __restrict__ dst, int* __restrict__ cursor,
                        int* __restrict__ perm) {
    int e = blockIdx.x * blockDim.x + threadIdx.x;
    if (e < N_EDGES) {
        int p = atomicAdd(&cursor[dst[e]], 1);
        perm[p] = e;
    }
}

// rel[r, c] = b_rel_l[c] + sum_k q[r,k] * W_rel_l[k, c]   (c = rt*DIM + d)
__global__ void k_rel(const float* __restrict__ q, const float* __restrict__ W_rel_l,
                      const float* __restrict__ b_rel_l, float* __restrict__ rel) {
    int idx = blockIdx.x * blockDim.x + threadIdx.x;
    if (idx >= BS * RELDIM) return;
    int r = idx / RELDIM;
    int c = idx % RELDIM;
    float acc = b_rel_l[c];
    #pragma unroll
    for (int k = 0; k < DIM; k++) acc += q[r * DIM + k] * W_rel_l[k * RELDIM + c];
    rel[idx] = acc;
}

// Fused: message gather (CSR) + boundary add + concat-linear-ReLU + pb scatter-max
__launch_bounds__(256)
__global__ void k_layer(const float* __restrict__ x_old, const float* __restrict__ pb_old,
                        const float* __restrict__ rel, const float* __restrict__ edge_attr,
                        const int* __restrict__ src, const int* __restrict__ etype,
                        const int* __restrict__ off, const int* __restrict__ perm,
                        const int* __restrict__ h0, const float* __restrict__ q,
                        const float* __restrict__ W_lin_l, const float* __restrict__ b_lin_l,
                        float* __restrict__ x_new, float* __restrict__ pb_new) {
    __shared__ float Wl[64 * DIM];
    __shared__ float bl[DIM];
    for (int i = threadIdx.x; i < 64 * DIM; i += blockDim.x) Wl[i] = W_lin_l[i];
    if (threadIdx.x < DIM) bl[threadIdx.x] = b_lin_l[threadIdx.x];
    __syncthreads();

    int idx = blockIdx.x * blockDim.x + threadIdx.x;
    if (idx >= BS * N_NODES) return;
    int r = idx / N_NODES;
    int n = idx % N_NODES;

    const float4* xrow4 = (const float4*)(x_old + (size_t)idx * DIM);
    float4 xr[8], ag[8];
    #pragma unroll
    for (int c = 0; c < 8; c++) {
        xr[c] = xrow4[c];
        ag[c] = make_float4(0.f, 0.f, 0.f, 0.f);
    }
    float pbm = pb_old[idx];

    int s0 = off[n], s1 = off[n + 1];
    const float* xbase = x_old + (size_t)r * N_NODES * DIM;
    const float* pbbase = pb_old + (size_t)r * N_NODES;
    const float* relr = rel + (size_t)r * RELDIM;
    for (int k = s0; k < s1; k++) {
        int e = perm[k];
        int s = src[e];
        int et = etype[e];
        const float4* xs = (const float4*)(xbase + (size_t)s * DIM);
        const float4* rl = (const float4*)(relr + (size_t)et * DIM);
        const float4* ea = (const float4*)(edge_attr + (size_t)e * DIM);
        #pragma unroll
        for (int c = 0; c < 8; c++) {
            float4 a = xs[c], bb = rl[c], t = ea[c];
            ag[c].x += a.x * (bb.x + t.x);
            ag[c].y += a.y * (bb.y + t.y);
            ag[c].z += a.z * (bb.z + t.z);
            ag[c].w += a.w * (bb.w + t.w);
        }
        pbm = fmaxf(pbm, pbbase[s]);
    }
    if (n == h0[r]) {
        const float4* qq = (const float4*)(q + r * DIM);
        #pragma unroll
        for (int c = 0; c < 8; c++) {
            float4 v = qq[c];
            ag[c].x += v.x; ag[c].y += v.y; ag[c].z += v.z; ag[c].w += v.w;
        }
    }

    const float* xrf = (const float*)xr;
    const float* agf = (const float*)ag;
    float* xo = x_new + (size_t)idx * DIM;
    #pragma unroll
    for (int j0 = 0; j0 < DIM; j0 += 4) {
        float acc[4];
        #pragma unroll
        for (int jj = 0; jj < 4; jj++) {
            float a = bl[j0 + jj];
            #pragma unroll
            for (int k = 0; k < DIM; k++) a += xrf[k] * Wl[k * DIM + j0 + jj];
            #pragma unroll
            for (int k = 0; k < DIM; k++) a += agf[k] * Wl[(DIM + k) * DIM + j0 + jj];
            acc[jj] = fmaxf(a, 0.f);
        }
        float4 o = make_float4(acc[0], acc[1], acc[2], acc[3]);
        *(float4*)(xo + j0) = o;
    }
    pb_new[idx] = pbm;
}

// Data-parallel epilogue: 1 block x 1024 threads, everything staged in LDS.
// No per-thread arrays -> nothing can spill to scratch.
__launch_bounds__(1024)
__global__ void k_final(const float* __restrict__ x, const float* __restrict__ pb,
                        const int* __restrict__ t_idx,
                        const float* __restrict__ W1, const float* __restrict__ b1,
                        const float* __restrict__ W2, const float* __restrict__ b2,
                        float* __restrict__ out) {
    __shared__ float sW1[DIM * DIM];     // 4 KB
    __shared__ float sW2[DIM * DIM];     // 4 KB
    __shared__ float sfeat[BATCH * NEG * DIM];  // 16 KB
    __shared__ float shid[BATCH * NEG * DIM];   // 16 KB
    const int t = threadIdx.x;
    const int NPAIR = BATCH * NEG;  // 128

    for (int i = t; i < DIM * DIM; i += 1024) { sW1[i] = W1[i]; sW2[i] = W2[i]; }

    // feat[pair][d] = mean over reps of x[(rep*BATCH+b)*N + t_idx] [d]
    for (int i = t; i < NPAIR * DIM; i += 1024) {
        int pair = i >> 5;          // /DIM
        int d = i & 31;
        int b = pair >> 5;          // /NEG
        int tt = t_idx[pair];       // rows 0..3 of t_idx == per-batch t (same across reps)
        float s = 0.f;
        #pragma unroll
        for (int rep = 0; rep < NREP; rep++)
            s += x[((size_t)(rep * BATCH + b) * N_NODES + tt) * DIM + d];
        sfeat[i] = s * (1.f / 3.f);
    }
    __syncthreads();

    // hid = relu(feat @ W1 + b1)
    for (int i = t; i < NPAIR * DIM; i += 1024) {
        int pair = i >> 5;
        int jj = i & 31;
        float a = b1[jj];
        #pragma unroll
        for (int k = 0; k < DIM; k++)
            a += sfeat[pair * DIM + k] * sW1[k * DIM + jj];  // broadcast + stride-1: conflict-free
        shid[i] = fmaxf(a, 0.f);
    }
    __syncthreads();

    // out = hid @ W2 + b2
    for (int i = t; i < NPAIR * DIM; i += 1024) {
        int pair = i >> 5;
        int jj = i & 31;
        float a = b2[jj];
        #pragma unroll
        for (int k = 0; k < DIM; k++)
            a += shid[pair * DIM + k] * sW2[k * DIM + jj];
        out[i] = a;
    }

    // path_boundary
    if (t < NPAIR) {
        int b = t >> 5;
        int tt = t_idx[t];
        float pm = 0.f;
        #pragma unroll
        for (int rep = 0; rep < NREP; rep++)
            pm = fmaxf(pm, pb[(size_t)(rep * BATCH + b) * N_NODES + tt]);
        out[NPAIR * DIM + t] = pm;
    }
}

// ---------------------------------------------------------------------
extern "C" void kernel_launch(void* const* d_in, const int* in_sizes, int n_in,
                              void* d_out, int out_size, void* d_ws, size_t ws_size,
                              hipStream_t stream) {
    const int* batch = (const int*)d_in[0];
    const int* edge_index = (const int*)d_in[1];
    const int* edge_type = (const int*)d_in[2];
    const float* edge_attr = (const float*)d_in[3];
    // d_in[4] = num_nodes (hard-coded N_NODES, fixed by setup)
    const float* start_query = (const float*)d_in[5];
    const float* W_rel = (const float*)d_in[6];
    const float* b_rel = (const float*)d_in[7];
    const float* W_lin = (const float*)d_in[8];
    const float* b_lin = (const float*)d_in[9];
    const float* W_mlp1 = (const float*)d_in[10];
    const float* b_mlp1 = (const float*)d_in[11];
    const float* W_mlp2 = (const float*)d_in[12];
    const float* b_mlp2 = (const float*)d_in[13];

    float* wf = (float*)d_ws;
    int* wi = (int*)(wf + FLOAT_TOTAL);
    size_t need = FLOAT_TOTAL * sizeof(float) + INT_TOTAL * sizeof(int);
    if (ws_size < need) return;  // fail loudly via correctness check

    float* x_a = wf + XO_A;
    float* x_b = wf + XO_B;
    float* pb_a = wf + PBO_A;
    float* pb_b = wf + PBO_B;
    float* rel = wf + RELO;
    float* q = wf + QO;
    int* h0 = wi + IO_H0;
    int* t_idx = wi + IO_TIDX;
    int* counts = wi + IO_COUNTS;
    int* off = wi + IO_OFF;
    int* cursor = wi + IO_CURSOR;
    int* perm = wi + IO_PERM;

    const int* src = edge_index;
    const int* dst = edge_index + N_EDGES;

    // zero what must be zero (ws is poisoned before every call)
    hipMemsetAsync(x_a, 0, (size_t)BS * N_NODES * DIM * sizeof(float), stream);
    hipMemsetAsync(pb_a, 0, (size_t)BS * N_NODES * sizeof(float), stream);
    hipMemsetAsync(counts, 0, (size_t)N_NODES * sizeof(int), stream);

    k_init<<<1, 64, 0, stream>>>(batch, start_query, x_a, pb_a, q, h0, t_idx);

    // CSR by dst
    int eb = (N_EDGES + 255) / 256;
    k_count<<<eb, 256, 0, stream>>>(dst, counts);
    k_scan<<<1, 1024, 0, stream>>>(counts, off, cursor);
    k_place<<<eb, 256, 0, stream>>>(dst, cursor, perm);

    float* x_cur = x_a;
    float* x_nxt = x_b;
    float* pb_cur = pb_a;
    float* pb_nxt = pb_b;
    int relb = (BS * RELDIM + 255) / 256;
    int nb = (BS * N_NODES + 255) / 256;
    for (int l = 0; l < NLAYERS; l++) {
        k_rel<<<relb, 256, 0, stream>>>(q, W_rel + (size_t)l * DIM * RELDIM,
                                        b_rel + (size_t)l * RELDIM, rel);
        k_layer<<<nb, 256, 0, stream>>>(x_cur, pb_cur, rel, edge_attr, src, edge_type,
                                        off, perm, h0, q,
                                        W_lin + (size_t)l * 64 * DIM,
                                        b_lin + (size_t)l * DIM,
                                        x_nxt, pb_nxt);
        float* tx = x_cur; x_cur = x_nxt; x_nxt = tx;
        float* tp = pb_cur; pb_cur = pb_nxt; pb_nxt = tp;
    }

    k_final<<<1, 1024, 0, stream>>>(x_cur, pb_cur, t_idx, W_mlp1, b_mlp1, W_mlp2, b_mlp2,
                                    (float*)d_out);
}

// Round 4
// 394.835 us; speedup vs baseline: 2.9586x; 1.5773x over previous
//
#include <hip/hip_runtime.h>

#define N_NODES 20000
#define N_EDGES 100000
#define DIM 32
#define R2 100
#define NLAYERS 4
#define BATCH 4
#define NEG 32
#define NREP 3
#define BS (NREP * BATCH)          // 12
#define RELDIM (R2 * DIM)          // 3200
#define NCHUNK (N_NODES / 32)      // 625 node-chunks of 32
#define GRID_LAYER (((NCHUNK + 7) / 8) * BS * 8)  // 79*12*8 = 7584

// ---------------- workspace layout (floats then ints) ----------------
#define XO_A 0
#define XO_B (XO_A + (size_t)BS * N_NODES * DIM)
#define PBO_A (XO_B + (size_t)BS * N_NODES * DIM)
#define PBO_B (PBO_A + (size_t)BS * N_NODES)
#define RELO (PBO_B + (size_t)BS * N_NODES)
#define QO (RELO + (size_t)NLAYERS * BS * RELDIM)
#define FLOAT_TOTAL (QO + (size_t)BS * DIM)

#define IO_H0 0
#define IO_TIDX (IO_H0 + BS)
#define IO_COUNTS (IO_TIDX + BS * NEG)
#define IO_OFF (IO_COUNTS + N_NODES)
#define IO_CURSOR (IO_OFF + N_NODES + 1)
#define IO_PERM (IO_CURSOR + N_NODES)
#define INT_TOTAL (IO_PERM + N_EDGES)

// ---------------------------------------------------------------------
__global__ void k_init(const int* __restrict__ batch,
                       const float* __restrict__ start_query,
                       float* __restrict__ q, int* __restrict__ h0,
                       int* __restrict__ t_idx) {
    int r = threadIdx.x;
    if (r >= BS) return;
    int b = r % BATCH, rep = r / BATCH;
    int h00 = batch[(b * NEG + 0) * 2 + 0];
    bool is_t_neg = true;
    for (int j = 0; j < NEG; j++)
        if (batch[(b * NEG + j) * 2 + 0] != h00) { is_t_neg = false; break; }
    int hsel = is_t_neg ? 0 : 1;
    int h0v = batch[(b * NEG + 0) * 2 + hsel];
    h0[r] = h0v;
    for (int j = 0; j < NEG; j++)
        t_idx[r * NEG + j] = batch[(b * NEG + j) * 2 + (1 - hsel)];
    for (int d = 0; d < DIM; d++) q[r * DIM + d] = start_query[rep * DIM + d];
}

__global__ void k_count(const int* __restrict__ dst, int* __restrict__ counts) {
    int e = blockIdx.x * blockDim.x + threadIdx.x;
    if (e < N_EDGES) atomicAdd(&counts[dst[e]], 1);
}

__global__ void k_scan(const int* __restrict__ counts, int* __restrict__ off,
                       int* __restrict__ cursor) {
    __shared__ int sd[1024];
    int t = threadIdx.x;
    const int CH = (N_NODES + 1023) / 1024;  // 20
    int base = t * CH;
    int sum = 0;
    for (int i = 0; i < CH; i++) {
        int idx = base + i;
        if (idx < N_NODES) sum += counts[idx];
    }
    sd[t] = sum;
    __syncthreads();
    for (int o = 1; o < 1024; o <<= 1) {
        int v = (t >= o) ? sd[t - o] : 0;
        __syncthreads();
        sd[t] += v;
        __syncthreads();
    }
    int excl = sd[t] - sum;
    int run = excl;
    for (int i = 0; i < CH; i++) {
        int idx = base + i;
        if (idx < N_NODES) {
            off[idx] = run;
            cursor[idx] = run;
            run += counts[idx];
        }
    }
    if (t == 1023) off[N_NODES] = sd[1023];
}

__global__ void k_place(const int* __restrict__ dst, int* __restrict__ cursor,
                        int* __restrict__ perm) {
    int e = blockIdx.x * blockDim.x + threadIdx.x;
    if (e < N_EDGES) {
        int p = atomicAdd(&cursor[dst[e]], 1);
        perm[p] = e;
    }
}

// rel[l][r][c] for all 4 layers in one launch
__global__ void k_rel_all(const float* __restrict__ q, const float* __restrict__ W_rel,
                          const float* __restrict__ b_rel, float* __restrict__ rel) {
    int idx = blockIdx.x * blockDim.x + threadIdx.x;
    if (idx >= NLAYERS * BS * RELDIM) return;
    int l = idx / (BS * RELDIM);
    int rem = idx - l * (BS * RELDIM);
    int r = rem / RELDIM;
    int c = rem - r * RELDIM;
    const float* W = W_rel + (size_t)l * DIM * RELDIM;
    float acc = b_rel[l * RELDIM + c];
    #pragma unroll
    for (int k = 0; k < DIM; k++) acc += q[r * DIM + k] * W[(size_t)k * RELDIM + c];
    rel[idx] = acc;
}

// Fused layer: 8 lanes per (r,node). Lane owns a float4 dim-slice.
// L0: x_old == boundary (implicit; zero except q at h0) -> no x/pb loads at all.
// Block swizzle: all 12 r-blocks of a node-chunk land on the same XCD (p%8==chunk%8).
template <bool L0>
__launch_bounds__(256)
__global__ void k_layer(const float* __restrict__ x_old, const float* __restrict__ pb_old,
                        const float* __restrict__ rel_l, const float* __restrict__ edge_attr,
                        const int* __restrict__ src, const int* __restrict__ etype,
                        const int* __restrict__ off, const int* __restrict__ perm,
                        const int* __restrict__ h0, const float* __restrict__ q,
                        const float* __restrict__ W_lin_l, const float* __restrict__ b_lin_l,
                        float* __restrict__ x_new, float* __restrict__ pb_new) {
    int p = blockIdx.x;
    int cgrp = (p & 7) + 8 * ((p >> 3) / BS);
    int r = (p >> 3) % BS;
    if (cgrp >= NCHUNK) return;  // block-uniform, before any barrier

    __shared__ float sW[64 * DIM];   // 8 KB
    __shared__ float sB[DIM];
    __shared__ float sIn[32 * 68];   // 32 nodes x (64 concat + 4 pad) = 8.5 KB

    for (int i = threadIdx.x; i < 64 * DIM; i += 256) sW[i] = W_lin_l[i];
    if (threadIdx.x < DIM) sB[threadIdx.x] = b_lin_l[threadIdx.x];

    const int g = threadIdx.x >> 3;   // node within chunk 0..31
    const int l = threadIdx.x & 7;    // dim-slice lane 0..7
    const int n = cgrp * 32 + g;
    const size_t idx = (size_t)r * N_NODES + n;
    const int h0r = h0[r];

    const float4 q4 = *(const float4*)(q + r * DIM + l * 4);
    float4 xr4, ag4 = make_float4(0.f, 0.f, 0.f, 0.f);
    float pbm;
    if (L0) {
        xr4 = (n == h0r) ? q4 : make_float4(0.f, 0.f, 0.f, 0.f);
        pbm = (n == h0r) ? 1.f : 0.f;
    } else {
        xr4 = *(const float4*)(x_old + idx * DIM + l * 4);
        pbm = pb_old[idx];
    }

    const int s0 = off[n], s1 = off[n + 1];
    const float* xbase = x_old + (size_t)r * N_NODES * DIM;
    const float* pbbase = pb_old + (size_t)r * N_NODES;
    const float* relr = rel_l + (size_t)r * RELDIM;
    for (int k = s0; k < s1; k++) {
        int e = perm[k];
        int s = src[e];
        if (L0) {
            if (s == h0r) {
                int et = etype[e];
                float4 rl = *(const float4*)(relr + (size_t)et * DIM + l * 4);
                float4 ea = *(const float4*)(edge_attr + (size_t)e * DIM + l * 4);
                ag4.x += q4.x * (rl.x + ea.x);
                ag4.y += q4.y * (rl.y + ea.y);
                ag4.z += q4.z * (rl.z + ea.z);
                ag4.w += q4.w * (rl.w + ea.w);
                pbm = 1.f;
            }
        } else {
            int et = etype[e];
            float4 xs = *(const float4*)(xbase + (size_t)s * DIM + l * 4);
            float4 rl = *(const float4*)(relr + (size_t)et * DIM + l * 4);
            float4 ea = *(const float4*)(edge_attr + (size_t)e * DIM + l * 4);
            ag4.x += xs.x * (rl.x + ea.x);
            ag4.y += xs.y * (rl.y + ea.y);
            ag4.z += xs.z * (rl.z + ea.z);
            ag4.w += xs.w * (rl.w + ea.w);
            pbm = fmaxf(pbm, pbbase[s]);
        }
    }
    if (n == h0r) {  // agg += boundary
        ag4.x += q4.x; ag4.y += q4.y; ag4.z += q4.z; ag4.w += q4.w;
    }

    float* srow = sIn + g * 68;                 // 272 B rows: 16B-aligned, banks spread 4g%32
    *(float4*)(srow + l * 4) = xr4;             // concat [x | agg]
    *(float4*)(srow + 32 + l * 4) = ag4;
    __syncthreads();

    float4 acc = *(const float4*)(sB + l * 4);
    #pragma unroll
    for (int k4 = 0; k4 < 16; k4++) {
        float4 v = *(const float4*)(srow + k4 * 4);
        const float* wb = sW + (k4 * 4) * DIM + l * 4;
        float4 w0 = *(const float4*)(wb);
        float4 w1 = *(const float4*)(wb + DIM);
        float4 w2 = *(const float4*)(wb + 2 * DIM);
        float4 w3 = *(const float4*)(wb + 3 * DIM);
        acc.x += v.x * w0.x + v.y * w1.x + v.z * w2.x + v.w * w3.x;
        acc.y += v.x * w0.y + v.y * w1.y + v.z * w2.y + v.w * w3.y;
        acc.z += v.x * w0.z + v.y * w1.z + v.z * w2.z + v.w * w3.z;
        acc.w += v.x * w0.w + v.y * w1.w + v.z * w2.w + v.w * w3.w;
    }
    acc.x = fmaxf(acc.x, 0.f);
    acc.y = fmaxf(acc.y, 0.f);
    acc.z = fmaxf(acc.z, 0.f);
    acc.w = fmaxf(acc.w, 0.f);
    *(float4*)(x_new + idx * DIM + l * 4) = acc;
    if (l == 0) pb_new[idx] = pbm;
}

// Data-parallel epilogue: 1 block x 1024 threads, everything staged in LDS.
__launch_bounds__(1024)
__global__ void k_final(const float* __restrict__ x, const float* __restrict__ pb,
                        const int* __restrict__ t_idx,
                        const float* __restrict__ W1, const float* __restrict__ b1,
                        const float* __restrict__ W2, const float* __restrict__ b2,
                        float* __restrict__ out) {
    __shared__ float sW1[DIM * DIM];
    __shared__ float sW2[DIM * DIM];
    __shared__ float sfeat[BATCH * NEG * DIM];
    __shared__ float shid[BATCH * NEG * DIM];
    const int t = threadIdx.x;
    const int NPAIR = BATCH * NEG;  // 128

    for (int i = t; i < DIM * DIM; i += 1024) { sW1[i] = W1[i]; sW2[i] = W2[i]; }

    for (int i = t; i < NPAIR * DIM; i += 1024) {
        int pair = i >> 5;
        int d = i & 31;
        int b = pair >> 5;
        int tt = t_idx[pair];
        float s = 0.f;
        #pragma unroll
        for (int rep = 0; rep < NREP; rep++)
            s += x[((size_t)(rep * BATCH + b) * N_NODES + tt) * DIM + d];
        sfeat[i] = s * (1.f / 3.f);
    }
    __syncthreads();

    for (int i = t; i < NPAIR * DIM; i += 1024) {
        int pair = i >> 5;
        int jj = i & 31;
        float a = b1[jj];
        #pragma unroll
        for (int k = 0; k < DIM; k++)
            a += sfeat[pair * DIM + k] * sW1[k * DIM + jj];
        shid[i] = fmaxf(a, 0.f);
    }
    __syncthreads();

    for (int i = t; i < NPAIR * DIM; i += 1024) {
        int pair = i >> 5;
        int jj = i & 31;
        float a = b2[jj];
        #pragma unroll
        for (int k = 0; k < DIM; k++)
            a += shid[pair * DIM + k] * sW2[k * DIM + jj];
        out[i] = a;
    }

    if (t < NPAIR) {
        int b = t >> 5;
        int tt = t_idx[t];
        float pm = 0.f;
        #pragma unroll
        for (int rep = 0; rep < NREP; rep++)
            pm = fmaxf(pm, pb[(size_t)(rep * BATCH + b) * N_NODES + tt]);
        out[NPAIR * DIM + t] = pm;
    }
}

// ---------------------------------------------------------------------
extern "C" void kernel_launch(void* const* d_in, const int* in_sizes, int n_in,
                              void* d_out, int out_size, void* d_ws, size_t ws_size,
                              hipStream_t stream) {
    const int* batch = (const int*)d_in[0];
    const int* edge_index = (const int*)d_in[1];
    const int* edge_type = (const int*)d_in[2];
    const float* edge_attr = (const float*)d_in[3];
    const float* start_query = (const float*)d_in[5];
    const float* W_rel = (const float*)d_in[6];
    const float* b_rel = (const float*)d_in[7];
    const float* W_lin = (const float*)d_in[8];
    const float* b_lin = (const float*)d_in[9];
    const float* W_mlp1 = (const float*)d_in[10];
    const float* b_mlp1 = (const float*)d_in[11];
    const float* W_mlp2 = (const float*)d_in[12];
    const float* b_mlp2 = (const float*)d_in[13];

    float* wf = (float*)d_ws;
    int* wi = (int*)(wf + FLOAT_TOTAL);
    size_t need = FLOAT_TOTAL * sizeof(float) + INT_TOTAL * sizeof(int);
    if (ws_size < need) return;

    float* x_a = wf + XO_A;
    float* x_b = wf + XO_B;
    float* pb_a = wf + PBO_A;
    float* pb_b = wf + PBO_B;
    float* rel = wf + RELO;
    float* q = wf + QO;
    int* h0 = wi + IO_H0;
    int* t_idx = wi + IO_TIDX;
    int* counts = wi + IO_COUNTS;
    int* off = wi + IO_OFF;
    int* cursor = wi + IO_CURSOR;
    int* perm = wi + IO_PERM;

    const int* src = edge_index;
    const int* dst = edge_index + N_EDGES;

    hipMemsetAsync(counts, 0, (size_t)N_NODES * sizeof(int), stream);

    k_init<<<1, 64, 0, stream>>>(batch, start_query, q, h0, t_idx);

    int eb = (N_EDGES + 255) / 256;
    k_count<<<eb, 256, 0, stream>>>(dst, counts);
    k_scan<<<1, 1024, 0, stream>>>(counts, off, cursor);
    k_place<<<eb, 256, 0, stream>>>(dst, cursor, perm);

    int relb = (NLAYERS * BS * RELDIM + 255) / 256;  // 600
    k_rel_all<<<relb, 256, 0, stream>>>(q, W_rel, b_rel, rel);

    // layer 0 (boundary input, sparse fast path) -> x_a, pb_a
    k_layer<true><<<GRID_LAYER, 256, 0, stream>>>(
        x_a, pb_a, rel, edge_attr, src, edge_type, off, perm, h0, q,
        W_lin, b_lin, x_a, pb_a);

    float* x_cur = x_a;
    float* x_nxt = x_b;
    float* pb_cur = pb_a;
    float* pb_nxt = pb_b;
    for (int l = 1; l < NLAYERS; l++) {
        k_layer<false><<<GRID_LAYER, 256, 0, stream>>>(
            x_cur, pb_cur, rel + (size_t)l * BS * RELDIM, edge_attr, src, edge_type,
            off, perm, h0, q,
            W_lin + (size_t)l * 64 * DIM, b_lin + (size_t)l * DIM,
            x_nxt, pb_nxt);
        float* tx = x_cur; x_cur = x_nxt; x_nxt = tx;
        float* tp = pb_cur; pb_cur = pb_nxt; pb_nxt = tp;
    }

    k_final<<<1, 1024, 0, stream>>>(x_cur, pb_cur, t_idx, W_mlp1, b_mlp1, W_mlp2, b_mlp2,
                                    (float*)d_out);
}

// Round 6
// 376.261 us; speedup vs baseline: 3.1046x; 1.0494x over previous
//
#include <hip/hip_runtime.h>

#define N_NODES 20000
#define N_EDGES 100000
#define DIM 32
#define R2 100
#define NLAYERS 4
#define BATCH 4
#define NEG 32
#define NREP 3
#define BS (NREP * BATCH)          // 12
#define RELDIM (R2 * DIM)          // 3200

#define NPB 4                      // nodes per block
#define TPN 96                     // threads per node = 12 r * 8 lanes
#define LBLK (NPB * TPN)           // 384
#define GRID_LAYER (N_NODES / NPB) // 5000

// ---------------- workspace layout (floats then ints) ----------------
// x: [N][BS][DIM] node-major; pb: [N][BS]; rel: [L][R2][BS][DIM]
#define XO_A 0
#define XO_B (XO_A + (size_t)N_NODES * BS * DIM)
#define PBO_A (XO_B + (size_t)N_NODES * BS * DIM)
#define PBO_B (PBO_A + (size_t)N_NODES * BS)
#define RELO (PBO_B + (size_t)N_NODES * BS)
#define QO (RELO + (size_t)NLAYERS * R2 * BS * DIM)
#define FLOAT_TOTAL (QO + (size_t)BS * DIM)

#define IO_H0 0
#define IO_TIDX (IO_H0 + BS)
#define IO_COUNTS (IO_TIDX + BS * NEG)
#define IO_OFF (IO_COUNTS + N_NODES)
#define IO_CURSOR (IO_OFF + N_NODES + 1)
#define IO_PERM (IO_CURSOR + N_NODES)
#define INT_TOTAL (IO_PERM + N_EDGES)

// ---------------------------------------------------------------------
__global__ void k_init(const int* __restrict__ batch,
                       const float* __restrict__ start_query,
                       float* __restrict__ q, int* __restrict__ h0,
                       int* __restrict__ t_idx) {
    int r = threadIdx.x;
    if (r >= BS) return;
    int b = r % BATCH, rep = r / BATCH;
    int h00 = batch[(b * NEG + 0) * 2 + 0];
    bool is_t_neg = true;
    for (int j = 0; j < NEG; j++)
        if (batch[(b * NEG + j) * 2 + 0] != h00) { is_t_neg = false; break; }
    int hsel = is_t_neg ? 0 : 1;
    int h0v = batch[(b * NEG + 0) * 2 + hsel];
    h0[r] = h0v;
    for (int j = 0; j < NEG; j++)
        t_idx[r * NEG + j] = batch[(b * NEG + j) * 2 + (1 - hsel)];
    for (int d = 0; d < DIM; d++) q[r * DIM + d] = start_query[rep * DIM + d];
}

__global__ void k_count(const int* __restrict__ dst, int* __restrict__ counts) {
    int e = blockIdx.x * blockDim.x + threadIdx.x;
    if (e < N_EDGES) atomicAdd(&counts[dst[e]], 1);
}

__global__ void k_scan(const int* __restrict__ counts, int* __restrict__ off,
                       int* __restrict__ cursor) {
    __shared__ int sd[1024];
    int t = threadIdx.x;
    const int CH = (N_NODES + 1023) / 1024;  // 20
    int base = t * CH;
    int sum = 0;
    for (int i = 0; i < CH; i++) {
        int idx = base + i;
        if (idx < N_NODES) sum += counts[idx];
    }
    sd[t] = sum;
    __syncthreads();
    for (int o = 1; o < 1024; o <<= 1) {
        int v = (t >= o) ? sd[t - o] : 0;
        __syncthreads();
        sd[t] += v;
        __syncthreads();
    }
    int excl = sd[t] - sum;
    int run = excl;
    for (int i = 0; i < CH; i++) {
        int idx = base + i;
        if (idx < N_NODES) {
            off[idx] = run;
            cursor[idx] = run;
            run += counts[idx];
        }
    }
    if (t == 1023) off[N_NODES] = sd[1023];
}

__global__ void k_place(const int* __restrict__ dst, int* __restrict__ cursor,
                        int* __restrict__ perm) {
    int e = blockIdx.x * blockDim.x + threadIdx.x;
    if (e < N_EDGES) {
        int p = atomicAdd(&cursor[dst[e]], 1);
        perm[p] = e;
    }
}

// rel[l][et][r][d] = b_rel[l][et*32+d] + sum_k q[r,k] * W_rel[l][k][et*32+d]
__global__ void k_rel_all(const float* __restrict__ q, const float* __restrict__ W_rel,
                          const float* __restrict__ b_rel, float* __restrict__ rel) {
    int idx = blockIdx.x * blockDim.x + threadIdx.x;
    if (idx >= NLAYERS * R2 * BS * DIM) return;
    int d = idx & 31;
    int r = (idx >> 5) % BS;
    int et = (idx / (BS * DIM)) % R2;
    int l = idx / (R2 * BS * DIM);
    int c = et * DIM + d;
    const float* W = W_rel + (size_t)l * DIM * RELDIM;
    float acc = b_rel[l * RELDIM + c];
    #pragma unroll
    for (int k = 0; k < DIM; k++) acc += q[r * DIM + k] * W[(size_t)k * RELDIM + c];
    rel[idx] = acc;
}

// Fused layer, all 12 r's per node in one pass.
// thread = node_in_block*96 + r*8 + l ; lane owns float4 dim-slice l of row r.
// Per edge: x[src] and rel[et] are 1536 B contiguous blobs, coalesced across 96 lanes.
template <bool L0>
__launch_bounds__(LBLK)
__global__ void k_layer(const float* __restrict__ x_old, const float* __restrict__ pb_old,
                        const float* __restrict__ rel_l, const float* __restrict__ edge_attr,
                        const int* __restrict__ src, const int* __restrict__ etype,
                        const int* __restrict__ off, const int* __restrict__ perm,
                        const int* __restrict__ h0, const float* __restrict__ q,
                        const float* __restrict__ W_lin_l, const float* __restrict__ b_lin_l,
                        float* __restrict__ x_new, float* __restrict__ pb_new) {
    __shared__ float sW[64 * DIM];           // 8 KB
    __shared__ float sB[DIM];
    __shared__ float sIn[NPB * BS * 68];     // 4*12*68*4 = 13056 B

    for (int i = threadIdx.x; i < 64 * DIM; i += LBLK) sW[i] = W_lin_l[i];
    if (threadIdx.x < DIM) sB[threadIdx.x] = b_lin_l[threadIdx.x];

    const int gi = threadIdx.x / TPN;        // node in block 0..3
    const int t = threadIdx.x % TPN;
    const int r = t >> 3;                    // 0..11
    const int l = t & 7;                     // 0..7
    const int n = blockIdx.x * NPB + gi;

    const int h0r = h0[r];
    const float4 q4 = *(const float4*)(q + r * DIM + l * 4);

    float4 xr4, ag4 = make_float4(0.f, 0.f, 0.f, 0.f);
    float pbm;
    if (L0) {
        xr4 = (n == h0r) ? q4 : make_float4(0.f, 0.f, 0.f, 0.f);
        pbm = (n == h0r) ? 1.f : 0.f;
    } else {
        xr4 = *(const float4*)(x_old + ((size_t)n * BS + r) * DIM + l * 4);
        pbm = pb_old[n * BS + r];
    }

    const int s0 = off[n], s1 = off[n + 1];
    for (int k = s0; k < s1; k++) {
        int e = perm[k];
        int s = src[e];
        if (L0) {
            if (s == h0r) {
                int et = etype[e];
                float4 rl = *(const float4*)(rel_l + ((size_t)et * BS + r) * DIM + l * 4);
                float4 ea = *(const float4*)(edge_attr + (size_t)e * DIM + l * 4);
                ag4.x += q4.x * (rl.x + ea.x);
                ag4.y += q4.y * (rl.y + ea.y);
                ag4.z += q4.z * (rl.z + ea.z);
                ag4.w += q4.w * (rl.w + ea.w);
                pbm = 1.f;
            }
        } else {
            int et = etype[e];
            float4 xs = *(const float4*)(x_old + ((size_t)s * BS + r) * DIM + l * 4);
            float4 rl = *(const float4*)(rel_l + ((size_t)et * BS + r) * DIM + l * 4);
            float4 ea = *(const float4*)(edge_attr + (size_t)e * DIM + l * 4);
            ag4.x += xs.x * (rl.x + ea.x);
            ag4.y += xs.y * (rl.y + ea.y);
            ag4.z += xs.z * (rl.z + ea.z);
            ag4.w += xs.w * (rl.w + ea.w);
            pbm = fmaxf(pbm, pb_old[s * BS + r]);
        }
    }
    if (n == h0r) {  // agg += boundary
        ag4.x += q4.x; ag4.y += q4.y; ag4.z += q4.z; ag4.w += q4.w;
    }

    float* srow = sIn + (gi * BS + r) * 68;
    *(float4*)(srow + l * 4) = xr4;          // concat [x | agg]
    *(float4*)(srow + 32 + l * 4) = ag4;
    __syncthreads();                          // covers sW/sB/sIn

    float4 acc = *(const float4*)(sB + l * 4);
    #pragma unroll
    for (int k4 = 0; k4 < 16; k4++) {
        float4 v = *(const float4*)(srow + k4 * 4);
        const float* wb = sW + (k4 * 4) * DIM + l * 4;
        float4 w0 = *(const float4*)(wb);
        float4 w1 = *(const float4*)(wb + DIM);
        float4 w2 = *(const float4*)(wb + 2 * DIM);
        float4 w3 = *(const float4*)(wb + 3 * DIM);
        acc.x += v.x * w0.x + v.y * w1.x + v.z * w2.x + v.w * w3.x;
        acc.y += v.x * w0.y + v.y * w1.y + v.z * w2.y + v.w * w3.y;
        acc.z += v.x * w0.z + v.y * w1.z + v.z * w2.z + v.w * w3.z;
        acc.w += v.x * w0.w + v.y * w1.w + v.z * w2.w + v.w * w3.w;
    }
    acc.x = fmaxf(acc.x, 0.f);
    acc.y = fmaxf(acc.y, 0.f);
    acc.z = fmaxf(acc.z, 0.f);
    acc.w = fmaxf(acc.w, 0.f);
    *(float4*)(x_new + ((size_t)n * BS + r) * DIM + l * 4) = acc;
    if (l == 0) pb_new[n * BS + r] = pbm;
}

// Data-parallel epilogue: 1 block x 1024 threads, LDS-staged.
__launch_bounds__(1024)
__global__ void k_final(const float* __restrict__ x, const float* __restrict__ pb,
                        const int* __restrict__ t_idx,
                        const float* __restrict__ W1, const float* __restrict__ b1,
                        const float* __restrict__ W2, const float* __restrict__ b2,
                        float* __restrict__ out) {
    __shared__ float sW1[DIM * DIM];
    __shared__ float sW2[DIM * DIM];
    __shared__ float sfeat[BATCH * NEG * DIM];
    __shared__ float shid[BATCH * NEG * DIM];
    const int t = threadIdx.x;
    const int NPAIR = BATCH * NEG;  // 128

    for (int i = t; i < DIM * DIM; i += 1024) { sW1[i] = W1[i]; sW2[i] = W2[i]; }

    for (int i = t; i < NPAIR * DIM; i += 1024) {
        int pair = i >> 5;
        int d = i & 31;
        int b = pair >> 5;
        int tt = t_idx[pair];
        float s = 0.f;
        #pragma unroll
        for (int rep = 0; rep < NREP; rep++)
            s += x[((size_t)tt * BS + rep * BATCH + b) * DIM + d];
        sfeat[i] = s * (1.f / 3.f);
    }
    __syncthreads();

    for (int i = t; i < NPAIR * DIM; i += 1024) {
        int pair = i >> 5;
        int jj = i & 31;
        float a = b1[jj];
        #pragma unroll
        for (int k = 0; k < DIM; k++)
            a += sfeat[pair * DIM + k] * sW1[k * DIM + jj];
        shid[i] = fmaxf(a, 0.f);
    }
    __syncthreads();

    for (int i = t; i < NPAIR * DIM; i += 1024) {
        int pair = i >> 5;
        int jj = i & 31;
        float a = b2[jj];
        #pragma unroll
        for (int k = 0; k < DIM; k++)
            a += shid[pair * DIM + k] * sW2[k * DIM + jj];
        out[i] = a;
    }

    if (t < NPAIR) {
        int b = t >> 5;
        int tt = t_idx[t];
        float pm = 0.f;
        #pragma unroll
        for (int rep = 0; rep < NREP; rep++)
            pm = fmaxf(pm, pb[(size_t)tt * BS + rep * BATCH + b]);
        out[NPAIR * DIM + t] = pm;
    }
}

// ---------------------------------------------------------------------
extern "C" void kernel_launch(void* const* d_in, const int* in_sizes, int n_in,
                              void* d_out, int out_size, void* d_ws, size_t ws_size,
                              hipStream_t stream) {
    const int* batch = (const int*)d_in[0];
    const int* edge_index = (const int*)d_in[1];
    const int* edge_type = (const int*)d_in[2];
    const float* edge_attr = (const float*)d_in[3];
    const float* start_query = (const float*)d_in[5];
    const float* W_rel = (const float*)d_in[6];
    const float* b_rel = (const float*)d_in[7];
    const float* W_lin = (const float*)d_in[8];
    const float* b_lin = (const float*)d_in[9];
    const float* W_mlp1 = (const float*)d_in[10];
    const float* b_mlp1 = (const float*)d_in[11];
    const float* W_mlp2 = (const float*)d_in[12];
    const float* b_mlp2 = (const float*)d_in[13];

    float* wf = (float*)d_ws;
    int* wi = (int*)(wf + FLOAT_TOTAL);
    size_t need = FLOAT_TOTAL * sizeof(float) + INT_TOTAL * sizeof(int);
    if (ws_size < need) return;

    float* x_a = wf + XO_A;
    float* x_b = wf + XO_B;
    float* pb_a = wf + PBO_A;
    float* pb_b = wf + PBO_B;
    float* rel = wf + RELO;
    float* q = wf + QO;
    int* h0 = wi + IO_H0;
    int* t_idx = wi + IO_TIDX;
    int* counts = wi + IO_COUNTS;
    int* off = wi + IO_OFF;
    int* cursor = wi + IO_CURSOR;
    int* perm = wi + IO_PERM;

    const int* src = edge_index;
    const int* dst = edge_index + N_EDGES;

    hipMemsetAsync(counts, 0, (size_t)N_NODES * sizeof(int), stream);

    k_init<<<1, 64, 0, stream>>>(batch, start_query, q, h0, t_idx);

    int eb = (N_EDGES + 255) / 256;
    k_count<<<eb, 256, 0, stream>>>(dst, counts);
    k_scan<<<1, 1024, 0, stream>>>(counts, off, cursor);
    k_place<<<eb, 256, 0, stream>>>(dst, cursor, perm);

    int relb = (NLAYERS * R2 * BS * DIM + 255) / 256;  // 600
    k_rel_all<<<relb, 256, 0, stream>>>(q, W_rel, b_rel, rel);

    // layer 0 (boundary input, sparse fast path) -> x_a, pb_a
    k_layer<true><<<GRID_LAYER, LBLK, 0, stream>>>(
        x_a, pb_a, rel, edge_attr, src, edge_type, off, perm, h0, q,
        W_lin, b_lin, x_a, pb_a);

    float* x_cur = x_a;
    float* x_nxt = x_b;
    float* pb_cur = pb_a;
    float* pb_nxt = pb_b;
    for (int l = 1; l < NLAYERS; l++) {
        k_layer<false><<<GRID_LAYER, LBLK, 0, stream>>>(
            x_cur, pb_cur, rel + (size_t)l * R2 * BS * DIM, edge_attr, src, edge_type,
            off, perm, h0, q,
            W_lin + (size_t)l * 64 * DIM, b_lin + (size_t)l * DIM,
            x_nxt, pb_nxt);
        float* tx = x_cur; x_cur = x_nxt; x_nxt = tx;
        float* tp = pb_cur; pb_cur = pb_nxt; pb_nxt = tp;
    }

    k_final<<<1, 1024, 0, stream>>>(x_cur, pb_cur, t_idx, W_mlp1, b_mlp1, W_mlp2, b_mlp2,
                                    (float*)d_out);
}